// Round 3
// baseline (1259.941 us; speedup 1.0000x reference)
//
#include <hip/hip_runtime.h>
#include <hip/hip_bf16.h>

#define HH 96
#define WW 96
#define CC 21
#define NN (HH*WW)          // 9216
#define ROWSTRIDE (WW*CC)   // 2016
#define NELEM (NN*CC)       // 193536
#define RS 20               // spatial blur radius: exp(-400/18)=2e-10
#define TK 128              // staged m-tile
#define CHUNK 512           // m-chunk per block (4 tiles)
#define SKN 18              // 18*512 = 9216 m-splits
#define NPAR (2*CC + CC*CC) // 483 converted params

__device__ __forceinline__ float fexp(float x) {
#if __has_builtin(__builtin_amdgcn_exp2f)
    return __builtin_amdgcn_exp2f(x * 1.4426950408889634f);
#else
    return __expf(x);
#endif
}

// ---- dtype sniff: bf16 data never contains exp=0xFF patterns; fp32 data's
// low mantissa halves hit it ~0.4% of the time. Single block, no pre-zero needed.
__global__ void k_sniff(const unsigned short* __restrict__ u16, int* __restrict__ flag) {
    __shared__ int sfound;
    if (threadIdx.x == 0) sfound = 0;
    __syncthreads();
    int found = 0;
    for (int i = threadIdx.x; i < NELEM; i += 1024) {
        unsigned v = u16[i];
        if ((v & 0x7F80u) == 0x7F80u) found = 1;
    }
    if (found) sfound = 1;      // benign same-value race in LDS
    __syncthreads();
    if (threadIdx.x == 0) *flag = sfound;   // 1 = inputs are fp32, 0 = bf16
}

// Convert all inputs to fp32 per flag; build feat[m] = (8c0,8c1,8c2,32|c|^2).
__global__ void k_convert(const void* __restrict__ u, const void* __restrict__ img,
                          const void* __restrict__ wS, const void* __restrict__ wB,
                          const void* __restrict__ compat, const int* __restrict__ flag,
                          float* __restrict__ uf, float4* __restrict__ feat,
                          float* __restrict__ par) {
    const int f = *flag;
    int i = blockIdx.x * 256 + threadIdx.x;
    if (i >= NELEM) return;
    uf[i] = f ? ((const float*)u)[i]
              : __bfloat162float(((const __hip_bfloat16*)u)[i]);
    if (i < NN) {
        float c0, c1, c2;
        if (f) { const float* p = (const float*)img;
                 c0 = p[3*i]; c1 = p[3*i+1]; c2 = p[3*i+2]; }
        else   { const __hip_bfloat16* p = (const __hip_bfloat16*)img;
                 c0 = __bfloat162float(p[3*i]); c1 = __bfloat162float(p[3*i+1]);
                 c2 = __bfloat162float(p[3*i+2]); }
        feat[i] = make_float4(8.f*c0, 8.f*c1, 8.f*c2, 32.f*(c0*c0 + c1*c1 + c2*c2));
    }
    if (i < NPAR) {
        const void* src; int j;
        if (i < CC)        { src = wS;     j = i; }
        else if (i < 2*CC) { src = wB;     j = i - CC; }
        else               { src = compat; j = i - 2*CC; }
        par[i] = f ? ((const float*)src)[j]
                   : __bfloat162float(((const __hip_bfloat16*)src)[j]);
    }
}

__global__ void k_zero(float* __restrict__ dst) {
    int i = blockIdx.x * 256 + threadIdx.x;
    if (i < NELEM) dst[i] = 0.f;
}

__global__ void k_softmax(const float* __restrict__ src, float* __restrict__ dst) {
    int n = blockIdx.x * 256 + threadIdx.x;
    if (n >= NN) return;
    float v[CC];
    float mx = -1e30f;
    #pragma unroll
    for (int c = 0; c < CC; c++) { v[c] = src[n*CC + c]; mx = fmaxf(mx, v[c]); }
    float s = 0.f;
    #pragma unroll
    for (int c = 0; c < CC; c++) { v[c] = fexp(v[c] - mx); s += v[c]; }
    float inv = 1.f / s;
    #pragma unroll
    for (int c = 0; c < CC; c++) dst[n*CC + c] = v[c] * inv;
}

// Separable spatial Gaussian: exp(-(dy^2+dx^2)/18)
__global__ void k_blury(const float* __restrict__ src, float* __restrict__ dst) {
    int idx = blockIdx.x * 256 + threadIdx.x;
    if (idx >= NELEM) return;
    int y = idx / ROWSTRIDE;
    float acc = 0.f;
    #pragma unroll
    for (int dy = -RS; dy <= RS; dy++) {
        int yy = y + dy;
        if ((unsigned)yy < HH) {
            float w = fexp(-(float)(dy*dy) * (1.f/18.f));
            acc = fmaf(w, src[idx + dy*ROWSTRIDE], acc);
        }
    }
    dst[idx] = acc;
}

__global__ void k_blurx(const float* __restrict__ src, float* __restrict__ dst) {
    int idx = blockIdx.x * 256 + threadIdx.x;
    if (idx >= NELEM) return;
    int x = (idx / CC) % WW;
    float acc = 0.f;
    #pragma unroll
    for (int dx = -RS; dx <= RS; dx++) {
        int xx = x + dx;
        if ((unsigned)xx < WW) {
            float w = fexp(-(float)(dx*dx) * (1.f/18.f));
            acc = fmaf(w, src[idx + dx*CC], acc);
        }
    }
    dst[idx] = acc;
}

// Dense bilateral filter: bil[c][n] += sum_{m in chunk} K(n,m) p[m,c]
// Block = 1 wave; lane owns n = bx*64+tid; blockIdx.y = m-chunk; atomic output.
__global__ __launch_bounds__(64) void k_bilateral(
    const float* __restrict__ p, const float4* __restrict__ feat,
    float* __restrict__ bil)
{
    __shared__ float lds_p[CC][TK];   // transposed: p[c][m]
    __shared__ float lds_f[TK][8];    // f.x,f.y,f.z,f.w,ym,xm,pad,pad

    const int tid = threadIdx.x;
    const int n   = blockIdx.x * 64 + tid;
    const int sk  = blockIdx.y;

    const float yn = (float)(n / WW), xn = (float)(n % WW);
    const float4 fn = feat[n];

    float acc[CC];
    #pragma unroll
    for (int c = 0; c < CC; c++) acc[c] = 0.f;

    #pragma unroll 1
    for (int t4 = 0; t4 < CHUNK/TK; t4++) {
        const int m0 = sk*CHUNK + t4*TK;
        __syncthreads();
        const float4* gp = (const float4*)(p + (size_t)m0*CC);
        for (int idx = tid; idx < TK*CC/4; idx += 64) {
            float4 v = gp[idx];
            int e = idx*4;
            int m_ = e/CC;        lds_p[e - m_*CC][m_] = v.x;
            m_ = (e+1)/CC;        lds_p[e+1 - m_*CC][m_] = v.y;
            m_ = (e+2)/CC;        lds_p[e+2 - m_*CC][m_] = v.z;
            m_ = (e+3)/CC;        lds_p[e+3 - m_*CC][m_] = v.w;
        }
        for (int s = tid; s < TK; s += 64) {
            int m = m0 + s;
            float4 f = feat[m];
            lds_f[s][0] = f.x; lds_f[s][1] = f.y; lds_f[s][2] = f.z; lds_f[s][3] = f.w;
            lds_f[s][4] = (float)(m / WW);
            lds_f[s][5] = (float)(m % WW);
        }
        __syncthreads();

        #pragma unroll 1
        for (int g = 0; g < TK; g += 4) {
            float kb[4];
            #pragma unroll
            for (int j = 0; j < 4; j++) {
                float4 f = *(const float4*)&lds_f[g+j][0];
                float ym = lds_f[g+j][4], xm = lds_f[g+j][5];
                float dy = yn - ym, dx = xn - xm;
                float D  = fmaf(dy, dy, dx*dx);
                float a  = fmaf(fn.x, f.x, -f.w);
                a = fmaf(fn.y, f.y, a);
                a = fmaf(fn.z, f.z, a);
                a = a - fn.w;
                kb[j] = fexp(fmaf(D, -1.f/128.f, a));
            }
            #pragma unroll
            for (int c = 0; c < CC; c++) {
                float4 pv = *(const float4*)&lds_p[c][g];  // broadcast
                float t = acc[c];
                t = fmaf(kb[0], pv.x, t);
                t = fmaf(kb[1], pv.y, t);
                t = fmaf(kb[2], pv.z, t);
                t = fmaf(kb[3], pv.w, t);
                acc[c] = t;
            }
        }
    }
    #pragma unroll
    for (int c = 0; c < CC; c++)
        atomicAdd(&bil[(size_t)c*NN + n], acc[c]);   // coalesced over n
}

// Combine spatial+bilateral, apply compatibility, update q; last iter -> out.
__global__ void k_update(const float* __restrict__ bil, const float* __restrict__ s2,
                         const float* __restrict__ uf, const float* __restrict__ par,
                         const int* __restrict__ flag,
                         float* __restrict__ q, void* __restrict__ out, int write_out)
{
    __shared__ float sc[CC*CC];
    __shared__ float sws[CC], swb[CC];
    int tid = threadIdx.x;
    for (int i = tid; i < CC*CC; i += 256) sc[i] = par[2*CC + i];
    if (tid < CC) { sws[tid] = par[tid]; swb[tid] = par[CC + tid]; }
    __syncthreads();

    int n = blockIdx.x * 256 + tid;
    if (n >= NN) return;
    const int is_f32 = *flag;

    float msg[CC];
    #pragma unroll
    for (int c = 0; c < CC; c++)
        msg[c] = fmaf(s2[n*CC + c], sws[c], bil[(size_t)c*NN + n] * swb[c]);

    #pragma unroll
    for (int c = 0; c < CC; c++) {
        float pw = 0.f;
        #pragma unroll
        for (int cp = 0; cp < CC; cp++) pw = fmaf(msg[cp], sc[c*CC + cp], pw);
        float qv = uf[n*CC + c] - pw;
        q[n*CC + c] = qv;
        if (write_out) {
            if (is_f32) ((float*)out)[n*CC + c] = qv;
            else ((__hip_bfloat16*)out)[n*CC + c] = __float2bfloat16(qv);
        }
    }
}

extern "C" void kernel_launch(void* const* d_in, const int* in_sizes, int n_in,
                              void* d_out, int out_size, void* d_ws, size_t ws_size,
                              hipStream_t stream)
{
    float* ws = (float*)d_ws;
    int*   flag = (int*)ws;                  // ws[0]
    float* par  = ws + 16;                   // 512 slots
    float4* feat = (float4*)(ws + 528);      // 4*NN floats, 16B-aligned
    float* uf   = ws + 528 + 4*NN;           // NELEM
    float* p    = uf + NELEM;
    float* q    = p + NELEM;
    float* tmp  = q + NELEM;                 // blur temp, ALIASED as bil
    float* s2   = tmp + NELEM;
    // total ~ (528 + 36864 + 5*193536) * 4B ~= 4.02 MB

    k_sniff<<<1, 1024, 0, stream>>>((const unsigned short*)d_in[0], flag);
    k_convert<<<(NELEM + 255)/256, 256, 0, stream>>>(d_in[0], d_in[1], d_in[2],
                                                     d_in[3], d_in[4], flag,
                                                     uf, feat, par);

    for (int it = 0; it < 5; it++) {
        const float* src = (it == 0) ? uf : q;
        k_softmax<<<(NN + 255)/256, 256, 0, stream>>>(src, p);
        k_blury<<<(NELEM + 255)/256, 256, 0, stream>>>(p, tmp);
        k_blurx<<<(NELEM + 255)/256, 256, 0, stream>>>(tmp, s2);
        k_zero<<<(NELEM + 255)/256, 256, 0, stream>>>(tmp);   // tmp becomes bil
        k_bilateral<<<dim3(NN/64, SKN), 64, 0, stream>>>(p, feat, tmp);
        k_update<<<(NN + 255)/256, 256, 0, stream>>>(tmp, s2, uf, par, flag,
                                                     q, d_out, (it == 4) ? 1 : 0);
    }
}

// Round 4
// 805.191 us; speedup vs baseline: 1.5648x; 1.5648x over previous
//
#include <hip/hip_runtime.h>
#include <hip/hip_bf16.h>

#define HH 96
#define WW 96
#define CC 21
#define NN (HH*WW)          // 9216
#define ROWSTRIDE (WW*CC)   // 2016
#define NELEM (NN*CC)       // 193536
#define RS 20               // spatial blur radius: exp(-400/18)=2e-10
#define TK 128              // staged m-tile
#define CHUNK 256           // m-chunk per block (2 tiles)
#define SKN 36              // 36*256 = 9216 m-splits
#define NPAR (2*CC + CC*CC) // 483 converted params
#define L2E 1.4426950408889634f

__device__ __forceinline__ float fexp2(float x) {
    return __builtin_amdgcn_exp2f(x);
}
__device__ __forceinline__ float fexp(float x) {
    return __builtin_amdgcn_exp2f(x * L2E);
}

// ---- dtype sniff: bf16 data never contains exp=0xFF bit patterns; fp32 data's
// low mantissa halves hit it ~0.4% of the time.
__global__ void k_sniff(const unsigned short* __restrict__ u16, int* __restrict__ flag) {
    __shared__ int sfound;
    if (threadIdx.x == 0) sfound = 0;
    __syncthreads();
    int found = 0;
    for (int i = threadIdx.x; i < NELEM; i += 1024) {
        unsigned v = u16[i];
        if ((v & 0x7F80u) == 0x7F80u) found = 1;
    }
    if (found) sfound = 1;
    __syncthreads();
    if (threadIdx.x == 0) *flag = sfound;   // 1 = fp32 inputs, 0 = bf16
}

// Convert inputs to fp32; build feat[m] = (8c0, 8c1, 8c2, 32|c|^2); zero bil.
__global__ void k_convert(const void* __restrict__ u, const void* __restrict__ img,
                          const void* __restrict__ wS, const void* __restrict__ wB,
                          const void* __restrict__ compat, const int* __restrict__ flag,
                          float* __restrict__ uf, float4* __restrict__ feat,
                          float* __restrict__ par, float* __restrict__ bil) {
    const int f = *flag;
    int i = blockIdx.x * 256 + threadIdx.x;
    if (i >= NELEM) return;
    uf[i] = f ? ((const float*)u)[i]
              : __bfloat162float(((const __hip_bfloat16*)u)[i]);
    bil[i] = 0.f;
    if (i < NN) {
        float c0, c1, c2;
        if (f) { const float* p = (const float*)img;
                 c0 = p[3*i]; c1 = p[3*i+1]; c2 = p[3*i+2]; }
        else   { const __hip_bfloat16* p = (const __hip_bfloat16*)img;
                 c0 = __bfloat162float(p[3*i]); c1 = __bfloat162float(p[3*i+1]);
                 c2 = __bfloat162float(p[3*i+2]); }
        feat[i] = make_float4(8.f*c0, 8.f*c1, 8.f*c2, 32.f*(c0*c0 + c1*c1 + c2*c2));
    }
    if (i < NPAR) {
        const void* src; int j;
        if (i < CC)        { src = wS;     j = i; }
        else if (i < 2*CC) { src = wB;     j = i - CC; }
        else               { src = compat; j = i - 2*CC; }
        par[i] = f ? ((const float*)src)[j]
                   : __bfloat162float(((const __hip_bfloat16*)src)[j]);
    }
}

// Initial p = softmax(uf)  (iterations 1..4 get p from fused k_update)
__global__ void k_softmax(const float* __restrict__ src, float* __restrict__ dst) {
    int n = blockIdx.x * 256 + threadIdx.x;
    if (n >= NN) return;
    float v[CC];
    float mx = -1e30f;
    #pragma unroll
    for (int c = 0; c < CC; c++) { v[c] = src[n*CC + c]; mx = fmaxf(mx, v[c]); }
    float s = 0.f;
    #pragma unroll
    for (int c = 0; c < CC; c++) { v[c] = fexp(v[c] - mx); s += v[c]; }
    float inv = 1.f / s;
    #pragma unroll
    for (int c = 0; c < CC; c++) dst[n*CC + c] = v[c] * inv;
}

// Separable spatial Gaussian: exp(-(dy^2+dx^2)/18)
__global__ void k_blury(const float* __restrict__ src, float* __restrict__ dst) {
    int idx = blockIdx.x * 256 + threadIdx.x;
    if (idx >= NELEM) return;
    int y = idx / ROWSTRIDE;
    float acc = 0.f;
    #pragma unroll
    for (int dy = -RS; dy <= RS; dy++) {
        int yy = y + dy;
        if ((unsigned)yy < HH) {
            float w = fexp(-(float)(dy*dy) * (1.f/18.f));
            acc = fmaf(w, src[idx + dy*ROWSTRIDE], acc);
        }
    }
    dst[idx] = acc;
}

__global__ void k_blurx(const float* __restrict__ src, float* __restrict__ dst) {
    int idx = blockIdx.x * 256 + threadIdx.x;
    if (idx >= NELEM) return;
    int x = (idx / CC) % WW;
    float acc = 0.f;
    #pragma unroll
    for (int dx = -RS; dx <= RS; dx++) {
        int xx = x + dx;
        if ((unsigned)xx < WW) {
            float w = fexp(-(float)(dx*dx) * (1.f/18.f));
            acc = fmaf(w, src[idx + dx*CC], acc);
        }
    }
    dst[idx] = acc;
}

// Dense bilateral filter: bil[c][n] += sum_{m in chunk} K(n,m) p[m,c]
// Block = 4 waves sharing the staged tile; wave w owns n = bx*256 + tid.
__global__ __launch_bounds__(256) void k_bilateral(
    const float* __restrict__ p, const float4* __restrict__ feat,
    float* __restrict__ bil)
{
    __shared__ float lds_p[CC][TK];   // transposed: p[c][m]
    __shared__ float lds_f[TK][8];    // f.x,f.y,f.z, l2e*f.w, ym, xm, pad, pad

    const int tid = threadIdx.x;
    const int n   = blockIdx.x * 256 + tid;
    const int sk  = blockIdx.y;

    const float yn = (float)(n / WW), xn = (float)(n % WW);
    const float4 fn0 = feat[n];
    // fold log2(e) into the n-side so kb = exp2(dot + coords) directly
    const float fnx = L2E * fn0.x, fny = L2E * fn0.y, fnz = L2E * fn0.z;
    const float fnw = L2E * fn0.w;

    float acc[CC];
    #pragma unroll
    for (int c = 0; c < CC; c++) acc[c] = 0.f;

    #pragma unroll 1
    for (int t4 = 0; t4 < CHUNK/TK; t4++) {
        const int m0 = sk*CHUNK + t4*TK;
        __syncthreads();
        const float4* gp = (const float4*)(p + (size_t)m0*CC);
        for (int idx = tid; idx < TK*CC/4; idx += 256) {
            float4 v = gp[idx];
            int e = idx*4;
            int m_ = e/CC;        lds_p[e - m_*CC][m_] = v.x;
            m_ = (e+1)/CC;        lds_p[e+1 - m_*CC][m_] = v.y;
            m_ = (e+2)/CC;        lds_p[e+2 - m_*CC][m_] = v.z;
            m_ = (e+3)/CC;        lds_p[e+3 - m_*CC][m_] = v.w;
        }
        for (int s = tid; s < TK; s += 256) {
            int m = m0 + s;
            float4 f = feat[m];
            lds_f[s][0] = f.x; lds_f[s][1] = f.y; lds_f[s][2] = f.z;
            lds_f[s][3] = L2E * f.w;
            lds_f[s][4] = (float)(m / WW);
            lds_f[s][5] = (float)(m % WW);
        }
        __syncthreads();

        #pragma unroll 1
        for (int g = 0; g < TK; g += 4) {
            float kb[4];
            #pragma unroll
            for (int j = 0; j < 4; j++) {
                float4 f  = *(const float4*)&lds_f[g+j][0];
                float2 ymx = *(const float2*)&lds_f[g+j][4];
                float dy = yn - ymx.x, dx = xn - ymx.y;
                float D  = fmaf(dy, dy, dx*dx);
                float a  = fmaf(fnx, f.x, -f.w);      // f.w pre-scaled by l2e
                a = fmaf(fny, f.y, a);
                a = fmaf(fnz, f.z, a);
                a = a - fnw;
                kb[j] = fexp2(fmaf(D, -L2E/128.f, a));
            }
            #pragma unroll
            for (int c = 0; c < CC; c++) {
                float4 pv = *(const float4*)&lds_p[c][g];  // broadcast
                float t = acc[c];
                t = fmaf(kb[0], pv.x, t);
                t = fmaf(kb[1], pv.y, t);
                t = fmaf(kb[2], pv.z, t);
                t = fmaf(kb[3], pv.w, t);
                acc[c] = t;
            }
        }
    }
    #pragma unroll
    for (int c = 0; c < CC; c++)
        atomicAdd(&bil[(size_t)c*NN + n], acc[c]);   // coalesced over n
}

// Combine spatial+bilateral, compatibility transform, q-update, THEN fused
// softmax -> writes p for the next iteration. Last iter writes d_out instead.
// Also re-zeroes bil for the next iteration's atomics.
__global__ void k_update(float* __restrict__ bil, const float* __restrict__ s2,
                         const float* __restrict__ uf, const float* __restrict__ par,
                         const int* __restrict__ flag,
                         float* __restrict__ p, void* __restrict__ out, int last)
{
    __shared__ float sc[CC*CC];
    __shared__ float sws[CC], swb[CC];
    int tid = threadIdx.x;
    for (int i = tid; i < CC*CC; i += 256) sc[i] = par[2*CC + i];
    if (tid < CC) { sws[tid] = par[tid]; swb[tid] = par[CC + tid]; }
    __syncthreads();

    int n = blockIdx.x * 256 + tid;
    if (n >= NN) return;
    const int is_f32 = *flag;

    float msg[CC];
    #pragma unroll
    for (int c = 0; c < CC; c++) {
        msg[c] = fmaf(s2[n*CC + c], sws[c], bil[(size_t)c*NN + n] * swb[c]);
        bil[(size_t)c*NN + n] = 0.f;   // ready for next iteration
    }

    float qv[CC];
    float mx = -1e30f;
    #pragma unroll
    for (int c = 0; c < CC; c++) {
        float pw = 0.f;
        #pragma unroll
        for (int cp = 0; cp < CC; cp++) pw = fmaf(msg[cp], sc[c*CC + cp], pw);
        qv[c] = uf[n*CC + c] - pw;
        mx = fmaxf(mx, qv[c]);
    }

    if (last) {
        #pragma unroll
        for (int c = 0; c < CC; c++) {
            if (is_f32) ((float*)out)[n*CC + c] = qv[c];
            else ((__hip_bfloat16*)out)[n*CC + c] = __float2bfloat16(qv[c]);
        }
    } else {
        float s = 0.f;
        #pragma unroll
        for (int c = 0; c < CC; c++) { qv[c] = fexp(qv[c] - mx); s += qv[c]; }
        float inv = 1.f / s;
        #pragma unroll
        for (int c = 0; c < CC; c++) p[n*CC + c] = qv[c] * inv;
    }
}

extern "C" void kernel_launch(void* const* d_in, const int* in_sizes, int n_in,
                              void* d_out, int out_size, void* d_ws, size_t ws_size,
                              hipStream_t stream)
{
    float* ws = (float*)d_ws;
    int*   flag = (int*)ws;                  // ws[0]
    float* par  = ws + 16;                   // 512 slots
    float4* feat = (float4*)(ws + 528);      // 4*NN floats, 16B-aligned
    float* uf   = ws + 528 + 4*NN;           // NELEM
    float* p    = uf + NELEM;
    float* tmp  = p + NELEM;                 // blur-y temp
    float* s2   = tmp + NELEM;               // spatial_out
    float* bil  = s2 + NELEM;                // bilateral accumulator
    // total ~ (528 + 36864 + 5*193536) * 4B ~= 4.02 MB

    k_sniff<<<1, 1024, 0, stream>>>((const unsigned short*)d_in[0], flag);
    k_convert<<<(NELEM + 255)/256, 256, 0, stream>>>(d_in[0], d_in[1], d_in[2],
                                                     d_in[3], d_in[4], flag,
                                                     uf, feat, par, bil);
    k_softmax<<<(NN + 255)/256, 256, 0, stream>>>(uf, p);

    for (int it = 0; it < 5; it++) {
        k_blury<<<(NELEM + 255)/256, 256, 0, stream>>>(p, tmp);
        k_blurx<<<(NELEM + 255)/256, 256, 0, stream>>>(tmp, s2);
        k_bilateral<<<dim3(NN/256, SKN), 256, 0, stream>>>(p, feat, bil);
        k_update<<<(NN + 255)/256, 256, 0, stream>>>(bil, s2, uf, par, flag,
                                                     p, d_out, (it == 4) ? 1 : 0);
    }
}

// Round 5
// 486.206 us; speedup vs baseline: 2.5914x; 1.6561x over previous
//
#include <hip/hip_runtime.h>
#include <hip/hip_bf16.h>

#define HH 96
#define WW 96
#define CC 21
#define NN (HH*WW)          // 9216
#define NELEM (NN*CC)       // 193536
#define RS 20               // spatial blur radius: exp(-400/18)=2e-10
#define NPAR (2*CC + CC*CC)
#define L2E 1.4426950408889634f
#define MCHUNK 384
#define SKM 24              // 24*384 = 9216 m-splits
#define MSTEPS (MCHUNK/16)  // 24

typedef short bf16x8 __attribute__((ext_vector_type(8)));   // 8 bf16 = 4 VGPRs
typedef float f32x16 __attribute__((ext_vector_type(16)));  // MFMA 32x32 acc

__device__ __forceinline__ float fexp2(float x) { return __builtin_amdgcn_exp2f(x); }
__device__ __forceinline__ float fexp(float x)  { return __builtin_amdgcn_exp2f(x * L2E); }

__device__ __forceinline__ short f2b(float f) {
    __hip_bfloat16 h = __float2bfloat16(f);
    short s; __builtin_memcpy(&s, &h, 2); return s;
}

// ---- dtype sniff: bf16 data never contains exp=0xFF bit patterns; fp32 data's
// low mantissa halves hit it ~0.4% of the time.
__global__ void k_sniff(const unsigned short* __restrict__ u16, int* __restrict__ flag) {
    __shared__ int sfound;
    if (threadIdx.x == 0) sfound = 0;
    __syncthreads();
    int found = 0;
    for (int i = threadIdx.x; i < NELEM; i += 1024) {
        unsigned v = u16[i];
        if ((v & 0x7F80u) == 0x7F80u) found = 1;
    }
    if (found) sfound = 1;
    __syncthreads();
    if (threadIdx.x == 0) *flag = sfound;   // 1 = fp32 inputs, 0 = bf16
}

// Convert inputs to fp32; build featx[m] (log2-prescaled symmetric features):
//   S_log2(n,m) = P_n + P_m + y'n y'm + x'n x'm + C_n . C_m ; K = exp2(S)
//   P = -L2E*((y^2+x^2)/128 + 32|c|^2),  y' = sqrt(2*L2E/128)*y,  C = sqrt(64*L2E)*c
__global__ void k_convert(const void* __restrict__ u, const void* __restrict__ img,
                          const void* __restrict__ wS, const void* __restrict__ wB,
                          const void* __restrict__ compat, const int* __restrict__ flag,
                          float* __restrict__ uf, float* __restrict__ featx,
                          float* __restrict__ par, float* __restrict__ bil) {
    const int f = *flag;
    int i = blockIdx.x * 256 + threadIdx.x;
    if (i >= NELEM) return;
    uf[i] = f ? ((const float*)u)[i]
              : __bfloat162float(((const __hip_bfloat16*)u)[i]);
    bil[i] = 0.f;
    if (i < NN) {
        float c0, c1, c2;
        if (f) { const float* p = (const float*)img;
                 c0 = p[3*i]; c1 = p[3*i+1]; c2 = p[3*i+2]; }
        else   { const __hip_bfloat16* p = (const __hip_bfloat16*)img;
                 c0 = __bfloat162float(p[3*i]); c1 = __bfloat162float(p[3*i+1]);
                 c2 = __bfloat162float(p[3*i+2]); }
        float ym = (float)(i / WW), xm = (float)(i % WW);
        const float sc = 0.15014029f;   // sqrt(2*L2E/128)
        const float cf = 9.6089787f;    // sqrt(64*L2E)
        featx[8*i + 0] = -L2E * (fmaf(ym, ym, xm*xm) * 0.0078125f
                                 + 32.f * (c0*c0 + c1*c1 + c2*c2));
        featx[8*i + 1] = sc * ym;
        featx[8*i + 2] = sc * xm;
        featx[8*i + 3] = cf * c0;
        featx[8*i + 4] = cf * c1;
        featx[8*i + 5] = cf * c2;
        featx[8*i + 6] = 0.f;
        featx[8*i + 7] = 0.f;
    }
    if (i < NPAR) {
        const void* src; int j;
        if (i < CC)        { src = wS;     j = i; }
        else if (i < 2*CC) { src = wB;     j = i - CC; }
        else               { src = compat; j = i - 2*CC; }
        par[i] = f ? ((const float*)src)[j]
                   : __bfloat162float(((const __hip_bfloat16*)src)[j]);
    }
}

// Initial p = softmax(uf); writes fp32 p (for blur) + bf16 transposed pT (for MFMA).
__global__ void k_softmax(const float* __restrict__ src, float* __restrict__ dst,
                          __hip_bfloat16* __restrict__ pT) {
    int n = blockIdx.x * 256 + threadIdx.x;
    if (n >= NN) return;
    float v[CC];
    float mx = -1e30f;
    #pragma unroll
    for (int c = 0; c < CC; c++) { v[c] = src[n*CC + c]; mx = fmaxf(mx, v[c]); }
    float s = 0.f;
    #pragma unroll
    for (int c = 0; c < CC; c++) { v[c] = fexp(v[c] - mx); s += v[c]; }
    float inv = 1.f / s;
    #pragma unroll
    for (int c = 0; c < CC; c++) {
        float pv = v[c] * inv;
        dst[n*CC + c] = pv;
        pT[(size_t)c*NN + n] = __float2bfloat16(pv);
    }
}

// Fused separable spatial Gaussian (y then x) for one channel per block.
__global__ __launch_bounds__(1024) void k_blur(const float* __restrict__ p,
                                               float* __restrict__ s2) {
    __shared__ float A[NN];
    __shared__ float B_[NN];
    __shared__ float w[RS + 1];
    const int c = blockIdx.x;
    const int tid = threadIdx.x;
    if (tid <= RS) w[tid] = fexp2(-(float)(tid*tid) * (L2E / 18.f));
    for (int i = tid; i < NN; i += 1024) A[i] = p[(size_t)i*CC + c];
    __syncthreads();
    for (int i = tid; i < NN; i += 1024) {
        int y = i / WW;
        float acc = A[i];                       // dy = 0, w = 1
        #pragma unroll
        for (int d = 1; d <= RS; d++) {
            float s = 0.f;
            if (y - d >= 0) s += A[i - d*WW];
            if (y + d < HH) s += A[i + d*WW];
            acc = fmaf(w[d], s, acc);
        }
        B_[i] = acc;
    }
    __syncthreads();
    for (int i = tid; i < NN; i += 1024) {
        int x = i % WW;
        float acc = B_[i];
        #pragma unroll
        for (int d = 1; d <= RS; d++) {
            float s = 0.f;
            if (x - d >= 0) s += B_[i - d];
            if (x + d < WW) s += B_[i + d];
            acc = fmaf(w[d], s, acc);
        }
        s2[(size_t)i*CC + c] = acc;
    }
}

// MFMA bilateral: bil[c][n] += sum_m pT[c][m] * K(n,m)
// D(32c x 32n) = A(32c x 16m = pT tile) * B(16m x 32n = K tile), v_mfma_f32_32x32x16_bf16.
// Wave: 2 n-tiles (64 n); block: 4 waves (256 n); grid (36, SKM).
// pT rows 21..31 are garbage -> pollute only D rows 21..31 (never stored).
__global__ __launch_bounds__(256) void k_bilateral(
    const __hip_bfloat16* __restrict__ pT,   // [32][NN] bf16
    const float* __restrict__ featx,         // [NN][8]
    float* __restrict__ bil)                 // [CC][NN]
{
    __shared__ float lds_h[MCHUNK * 8];
    const int tid  = threadIdx.x;
    const int wv   = tid >> 6, lane = tid & 63;
    const int quad = lane >> 5, lid = lane & 31;
    const int m0c  = blockIdx.y * MCHUNK;

    {   // stage featx chunk (coalesced float4 copy)
        const float4* src = (const float4*)(featx + (size_t)m0c * 8);
        float4* dst = (float4*)lds_h;
        for (int i = tid; i < MCHUNK * 2; i += 256) dst[i] = src[i];
    }
    __syncthreads();

    const int n0 = blockIdx.x * 256 + wv * 64 + lid;       // tile0; tile1 = n0+32
    const float4 g0a = *(const float4*)(featx + (size_t)n0 * 8);
    const float4 g0b = *(const float4*)(featx + (size_t)n0 * 8 + 4);
    const float4 g1a = *(const float4*)(featx + (size_t)(n0 + 32) * 8);
    const float4 g1b = *(const float4*)(featx + (size_t)(n0 + 32) * 8 + 4);

    f32x16 acc0, acc1;
    #pragma unroll
    for (int r = 0; r < 16; r++) { acc0[r] = 0.f; acc1[r] = 0.f; }

    #pragma unroll 1
    for (int step = 0; step < MSTEPS; step++) {
        const int m0 = m0c + step * 16;
        // A-frag: 8 consecutive bf16 p-values, row c=lid, k = quad*8+j (shared by both tiles)
        bf16x8 afrag = *(const bf16x8*)(pT + (size_t)lid * NN + m0 + quad * 8);

        const float* h = lds_h + (step * 16 + quad * 8) * 8;
        float kb0[8], kb1[8];
        #pragma unroll
        for (int j = 0; j < 8; j++) {
            float4 ha = *(const float4*)(h + j * 8);
            float4 hb = *(const float4*)(h + j * 8 + 4);
            float s0 = g0a.x + ha.x;
            s0 = fmaf(g0a.y, ha.y, s0);
            s0 = fmaf(g0a.z, ha.z, s0);
            s0 = fmaf(g0a.w, ha.w, s0);
            s0 = fmaf(g0b.x, hb.x, s0);
            s0 = fmaf(g0b.y, hb.y, s0);
            kb0[j] = fexp2(s0);
            float s1 = g1a.x + ha.x;
            s1 = fmaf(g1a.y, ha.y, s1);
            s1 = fmaf(g1a.z, ha.z, s1);
            s1 = fmaf(g1a.w, ha.w, s1);
            s1 = fmaf(g1b.x, hb.x, s1);
            s1 = fmaf(g1b.y, hb.y, s1);
            kb1[j] = fexp2(s1);
        }
        bf16x8 b0, b1;
        #pragma unroll
        for (int j = 0; j < 8; j++) { b0[j] = f2b(kb0[j]); b1[j] = f2b(kb1[j]); }

        acc0 = __builtin_amdgcn_mfma_f32_32x32x16_bf16(afrag, b0, acc0, 0, 0, 0);
        acc1 = __builtin_amdgcn_mfma_f32_32x32x16_bf16(afrag, b1, acc1, 0, 0, 0);
    }

    // D layout: col(n) = lid, row(c) = (r&3) + 8*(r>>2) + 4*quad
    #pragma unroll
    for (int r = 0; r < 16; r++) {
        int c = (r & 3) + 8 * (r >> 2) + 4 * quad;
        if (c < CC) {
            atomicAdd(&bil[(size_t)c * NN + n0],      acc0[r]);
            atomicAdd(&bil[(size_t)c * NN + n0 + 32], acc1[r]);
        }
    }
}

// Combine spatial+bilateral, compatibility, q-update, fused softmax -> p/pT.
// Re-zeroes bil for the next iteration.
__global__ void k_update(float* __restrict__ bil, const float* __restrict__ s2,
                         const float* __restrict__ uf, const float* __restrict__ par,
                         const int* __restrict__ flag,
                         float* __restrict__ p, __hip_bfloat16* __restrict__ pT,
                         void* __restrict__ out, int last)
{
    __shared__ float sc[CC*CC];
    __shared__ float sws[CC], swb[CC];
    int tid = threadIdx.x;
    for (int i = tid; i < CC*CC; i += 256) sc[i] = par[2*CC + i];
    if (tid < CC) { sws[tid] = par[tid]; swb[tid] = par[CC + tid]; }
    __syncthreads();

    int n = blockIdx.x * 256 + tid;
    if (n >= NN) return;
    const int is_f32 = *flag;

    float msg[CC];
    #pragma unroll
    for (int c = 0; c < CC; c++) {
        msg[c] = fmaf(s2[n*CC + c], sws[c], bil[(size_t)c*NN + n] * swb[c]);
        bil[(size_t)c*NN + n] = 0.f;
    }

    float qv[CC];
    float mx = -1e30f;
    #pragma unroll
    for (int c = 0; c < CC; c++) {
        float pw = 0.f;
        #pragma unroll
        for (int cp = 0; cp < CC; cp++) pw = fmaf(msg[cp], sc[c*CC + cp], pw);
        qv[c] = uf[n*CC + c] - pw;
        mx = fmaxf(mx, qv[c]);
    }

    if (last) {
        #pragma unroll
        for (int c = 0; c < CC; c++) {
            if (is_f32) ((float*)out)[n*CC + c] = qv[c];
            else ((__hip_bfloat16*)out)[n*CC + c] = __float2bfloat16(qv[c]);
        }
    } else {
        float s = 0.f;
        #pragma unroll
        for (int c = 0; c < CC; c++) { qv[c] = fexp(qv[c] - mx); s += qv[c]; }
        float inv = 1.f / s;
        #pragma unroll
        for (int c = 0; c < CC; c++) {
            float pv = qv[c] * inv;
            p[n*CC + c] = pv;
            pT[(size_t)c*NN + n] = __float2bfloat16(pv);
        }
    }
}

extern "C" void kernel_launch(void* const* d_in, const int* in_sizes, int n_in,
                              void* d_out, int out_size, void* d_ws, size_t ws_size,
                              hipStream_t stream)
{
    float* ws = (float*)d_ws;
    int*   flag  = (int*)ws;                     // [0..16)
    float* par   = ws + 16;                      // [16..528)
    float* featx = ws + 528;                     // NN*8 = 73728
    __hip_bfloat16* pT = (__hip_bfloat16*)(ws + 528 + NN*8);  // 32*NN bf16 = 147456 f
    float* uf  = ws + 528 + NN*8 + 16*NN;        // NELEM
    float* p   = uf + NELEM;                     // NELEM
    float* s2  = p + NELEM;                      // NELEM
    float* bil = s2 + NELEM;                     // NELEM
    // total ~ 995856 floats ~= 3.98 MB

    k_sniff<<<1, 1024, 0, stream>>>((const unsigned short*)d_in[0], flag);
    k_convert<<<(NELEM + 255)/256, 256, 0, stream>>>(d_in[0], d_in[1], d_in[2],
                                                     d_in[3], d_in[4], flag,
                                                     uf, featx, par, bil);
    k_softmax<<<(NN + 255)/256, 256, 0, stream>>>(uf, p, pT);

    for (int it = 0; it < 5; it++) {
        k_blur<<<CC, 1024, 0, stream>>>(p, s2);
        k_bilateral<<<dim3(NN/256, SKM), 256, 0, stream>>>(pT, featx, bil);
        k_update<<<(NN + 255)/256, 256, 0, stream>>>(bil, s2, uf, par, flag,
                                                     p, pT, d_out, (it == 4) ? 1 : 0);
    }
}

// Round 6
// 290.995 us; speedup vs baseline: 4.3298x; 1.6708x over previous
//
#include <hip/hip_runtime.h>
#include <hip/hip_bf16.h>

#define HH 96
#define WW 96
#define CC 21
#define NN (HH*WW)          // 9216
#define NELEM (NN*CC)       // 193536
#define RS 20               // blur radius: exp(-400/18)=2e-10 tail, negligible
#define NPAR (2*CC + CC*CC)
#define L2E 1.4426950408889634f
#define MCHUNK 384
#define SKM 24              // 24*384 = 9216 m-splits
#define MSTEPS (MCHUNK/16)  // 24
#define NBB (36*SKM)        // 864 bilateral blocks
#define NSTRIP 8            // 8 strips of 12 rows
#define NBLUR (CC*NSTRIP)   // 168 blur blocks
#define SROWS 12            // output rows per strip

typedef short bf16x8 __attribute__((ext_vector_type(8)));
typedef float f32x16 __attribute__((ext_vector_type(16)));

__device__ __forceinline__ float fexp2(float x) { return __builtin_amdgcn_exp2f(x); }
__device__ __forceinline__ float fexp(float x)  { return __builtin_amdgcn_exp2f(x * L2E); }

__device__ __forceinline__ short f2b(float f) {
    __hip_bfloat16 h = __float2bfloat16(f);
    short s; __builtin_memcpy(&s, &h, 2); return s;
}

// ---- dtype sniff: bf16 data never contains exp=0xFF bit patterns; fp32 data's
// low mantissa halves hit it ~0.4% of the time.
__global__ void k_sniff(const unsigned short* __restrict__ u16, int* __restrict__ flag) {
    __shared__ int sfound;
    if (threadIdx.x == 0) sfound = 0;
    __syncthreads();
    int found = 0;
    for (int i = threadIdx.x; i < NELEM; i += 1024) {
        unsigned v = u16[i];
        if ((v & 0x7F80u) == 0x7F80u) found = 1;
    }
    if (found) sfound = 1;
    __syncthreads();
    if (threadIdx.x == 0) *flag = sfound;   // 1 = fp32 inputs, 0 = bf16
}

// Fused prep: convert u -> uf (fp32 n-major), softmax -> pT (bf16 c-major),
// build featx, convert params, zero bil. Grid 36x256 (one thread per pixel).
__global__ __launch_bounds__(256) void k_prep(
    const void* __restrict__ u, const void* __restrict__ img,
    const void* __restrict__ wS, const void* __restrict__ wB,
    const void* __restrict__ compat, const int* __restrict__ flag,
    float* __restrict__ uf, float* __restrict__ featx, float* __restrict__ par,
    float* __restrict__ bil, __hip_bfloat16* __restrict__ pT)
{
    const int f = *flag;
    const int tid = threadIdx.x;
    const int n = blockIdx.x * 256 + tid;

    if (blockIdx.x == 0) {
        for (int i = tid; i < NPAR; i += 256) {
            const void* src; int j;
            if (i < CC)        { src = wS;     j = i; }
            else if (i < 2*CC) { src = wB;     j = i - CC; }
            else               { src = compat; j = i - 2*CC; }
            par[i] = f ? ((const float*)src)[j]
                       : __bfloat162float(((const __hip_bfloat16*)src)[j]);
        }
    }

    // featx[n]: log2-prescaled symmetric bilateral features
    {
        float c0, c1, c2;
        if (f) { const float* p = (const float*)img;
                 c0 = p[3*n]; c1 = p[3*n+1]; c2 = p[3*n+2]; }
        else   { const __hip_bfloat16* p = (const __hip_bfloat16*)img;
                 c0 = __bfloat162float(p[3*n]); c1 = __bfloat162float(p[3*n+1]);
                 c2 = __bfloat162float(p[3*n+2]); }
        float ym = (float)(n / WW), xm = (float)(n % WW);
        const float sc = 0.15014029f;   // sqrt(2*L2E/128)
        const float cf = 9.6089787f;    // sqrt(64*L2E)
        featx[8*n + 0] = -L2E * (fmaf(ym, ym, xm*xm) * 0.0078125f
                                 + 32.f * (c0*c0 + c1*c1 + c2*c2));
        featx[8*n + 1] = sc * ym;
        featx[8*n + 2] = sc * xm;
        featx[8*n + 3] = cf * c0;
        featx[8*n + 4] = cf * c1;
        featx[8*n + 5] = cf * c2;
        featx[8*n + 6] = 0.f;
        featx[8*n + 7] = 0.f;
    }

    float v[CC];
    float mx = -1e30f;
    #pragma unroll
    for (int c = 0; c < CC; c++) {
        float uv = f ? ((const float*)u)[n*CC + c]
                     : __bfloat162float(((const __hip_bfloat16*)u)[n*CC + c]);
        uf[n*CC + c] = uv;
        v[c] = uv;
        mx = fmaxf(mx, uv);
    }
    float s = 0.f;
    #pragma unroll
    for (int c = 0; c < CC; c++) { v[c] = fexp(v[c] - mx); s += v[c]; }
    float inv = 1.f / s;
    #pragma unroll
    for (int c = 0; c < CC; c++) {
        pT[(size_t)c*NN + n] = __float2bfloat16(v[c] * inv);
        bil[(size_t)c*NN + n] = 0.f;
    }
}

// Fused work kernel. Blocks [0, NBB): MFMA bilateral. Blocks [NBB, NBB+NBLUR):
// separable spatial blur (c-major, coalesced). Blur work hides behind bilateral.
__global__ __launch_bounds__(256) void k_work(
    const __hip_bfloat16* __restrict__ pT,   // [32][NN] bf16 (rows 21..31 garbage)
    const float* __restrict__ featx,         // [NN][8]
    float* __restrict__ bil,                 // [CC][NN] atomic accum
    float* __restrict__ s2T)                 // [CC][NN] spatial out
{
    __shared__ float smem[6176];             // bilateral: 3072; blur: 4992+1152
    const int tid = threadIdx.x;
    const int bid = blockIdx.x;

    if (bid < NBB) {
        // ---------------- bilateral: bil[c][n] += sum_m pT[c][m] * K(n,m)
        // D(32c x 32n) = A(32c x 16m) * B(16m x 32n), v_mfma_f32_32x32x16_bf16
        float* lds_h = smem;
        const int nblk = bid % 36, mblk = bid / 36;
        const int wv   = tid >> 6, lane = tid & 63;
        const int quad = lane >> 5, lid = lane & 31;
        const int m0c  = mblk * MCHUNK;

        {   // stage featx chunk (coalesced float4 copy)
            const float4* src = (const float4*)(featx + (size_t)m0c * 8);
            float4* dst = (float4*)lds_h;
            for (int i = tid; i < MCHUNK * 2; i += 256) dst[i] = src[i];
        }
        __syncthreads();

        const int n0 = nblk * 256 + wv * 64 + lid;       // tile0; tile1 = n0+32
        const float4 g0a = *(const float4*)(featx + (size_t)n0 * 8);
        const float4 g0b = *(const float4*)(featx + (size_t)n0 * 8 + 4);
        const float4 g1a = *(const float4*)(featx + (size_t)(n0 + 32) * 8);
        const float4 g1b = *(const float4*)(featx + (size_t)(n0 + 32) * 8 + 4);

        f32x16 acc0, acc1;
        #pragma unroll
        for (int r = 0; r < 16; r++) { acc0[r] = 0.f; acc1[r] = 0.f; }

        #pragma unroll 1
        for (int step = 0; step < MSTEPS; step++) {
            const int m0 = m0c + step * 16;
            bf16x8 afrag = *(const bf16x8*)(pT + (size_t)lid * NN + m0 + quad * 8);

            const float* h = lds_h + (step * 16 + quad * 8) * 8;
            float kb0[8], kb1[8];
            #pragma unroll
            for (int j = 0; j < 8; j++) {
                float4 ha = *(const float4*)(h + j * 8);
                float4 hb = *(const float4*)(h + j * 8 + 4);
                float s0 = g0a.x + ha.x;
                s0 = fmaf(g0a.y, ha.y, s0);
                s0 = fmaf(g0a.z, ha.z, s0);
                s0 = fmaf(g0a.w, ha.w, s0);
                s0 = fmaf(g0b.x, hb.x, s0);
                s0 = fmaf(g0b.y, hb.y, s0);
                kb0[j] = fexp2(s0);
                float s1 = g1a.x + ha.x;
                s1 = fmaf(g1a.y, ha.y, s1);
                s1 = fmaf(g1a.z, ha.z, s1);
                s1 = fmaf(g1a.w, ha.w, s1);
                s1 = fmaf(g1b.x, hb.x, s1);
                s1 = fmaf(g1b.y, hb.y, s1);
                kb1[j] = fexp2(s1);
            }
            bf16x8 b0, b1;
            #pragma unroll
            for (int j = 0; j < 8; j++) { b0[j] = f2b(kb0[j]); b1[j] = f2b(kb1[j]); }

            acc0 = __builtin_amdgcn_mfma_f32_32x32x16_bf16(afrag, b0, acc0, 0, 0, 0);
            acc1 = __builtin_amdgcn_mfma_f32_32x32x16_bf16(afrag, b1, acc1, 0, 0, 0);
        }

        // D layout: col(n) = lid, row(c) = (r&3) + 8*(r>>2) + 4*quad
        #pragma unroll
        for (int r = 0; r < 16; r++) {
            int c = (r & 3) + 8 * (r >> 2) + 4 * quad;
            if (c < CC) {
                atomicAdd(&bil[(size_t)c * NN + n0],      acc0[r]);
                atomicAdd(&bil[(size_t)c * NN + n0 + 32], acc1[r]);
            }
        }
    } else {
        // ---------------- spatial blur, one (channel, 12-row strip) per block
        __shared__ float w_s[RS + 1];
        float* A  = smem;            // up to 52 rows x 96
        float* B2 = smem + 4992;     // 12 rows x 96

        const int b2 = bid - NBB;
        const int c = b2 % CC;
        const int strip = b2 / CC;
        const int y0 = strip * SROWS;
        const int ylo = (y0 - RS < 0) ? 0 : y0 - RS;
        const int yhi = (y0 + SROWS - 1 + RS > HH - 1) ? HH - 1 : y0 + SROWS - 1 + RS;
        const int nrows = yhi - ylo + 1;

        if (tid <= RS) w_s[tid] = fexp2(-(float)(tid*tid) * (L2E / 18.f));
        const __hip_bfloat16* src = pT + (size_t)c * NN + ylo * WW;
        for (int i = tid; i < nrows * WW; i += 256)
            A[i] = __bfloat162float(src[i]);
        __syncthreads();

        for (int i = tid; i < SROWS * WW; i += 256) {
            const int yo = y0 + i / WW;
            const int x  = i % WW;
            float acc = A[(yo - ylo) * WW + x];
            #pragma unroll
            for (int d = 1; d <= RS; d++) {
                float s = 0.f;
                if (yo - d >= 0)  s += A[(yo - d - ylo) * WW + x];
                if (yo + d < HH)  s += A[(yo + d - ylo) * WW + x];
                acc = fmaf(w_s[d], s, acc);
            }
            B2[i] = acc;
        }
        __syncthreads();

        for (int i = tid; i < SROWS * WW; i += 256) {
            const int r = i / WW, x = i % WW;
            float acc = B2[i];
            #pragma unroll
            for (int d = 1; d <= RS; d++) {
                float s = 0.f;
                if (x - d >= 0)  s += B2[r * WW + x - d];
                if (x + d < WW)  s += B2[r * WW + x + d];
                acc = fmaf(w_s[d], s, acc);
            }
            s2T[(size_t)c * NN + (y0 + r) * WW + x] = acc;
        }
    }
}

// Combine spatial+bilateral, compatibility, q-update, fused softmax -> pT.
// Re-zeroes bil. Last iter writes d_out instead.
__global__ __launch_bounds__(256) void k_update(
    float* __restrict__ bil, const float* __restrict__ s2T,
    const float* __restrict__ uf, const float* __restrict__ par,
    const int* __restrict__ flag,
    __hip_bfloat16* __restrict__ pT, void* __restrict__ out, int last)
{
    __shared__ float sc[CC*CC];
    __shared__ float sws[CC], swb[CC];
    int tid = threadIdx.x;
    for (int i = tid; i < CC*CC; i += 256) sc[i] = par[2*CC + i];
    if (tid < CC) { sws[tid] = par[tid]; swb[tid] = par[CC + tid]; }
    __syncthreads();

    int n = blockIdx.x * 256 + tid;
    const int is_f32 = *flag;

    float msg[CC];
    #pragma unroll
    for (int c = 0; c < CC; c++) {
        msg[c] = fmaf(s2T[(size_t)c*NN + n], sws[c], bil[(size_t)c*NN + n] * swb[c]);
        bil[(size_t)c*NN + n] = 0.f;
    }

    float qv[CC];
    float mx = -1e30f;
    #pragma unroll
    for (int c = 0; c < CC; c++) {
        float pw = 0.f;
        #pragma unroll
        for (int cp = 0; cp < CC; cp++) pw = fmaf(msg[cp], sc[c*CC + cp], pw);
        qv[c] = uf[n*CC + c] - pw;
        mx = fmaxf(mx, qv[c]);
    }

    if (last) {
        #pragma unroll
        for (int c = 0; c < CC; c++) {
            if (is_f32) ((float*)out)[n*CC + c] = qv[c];
            else ((__hip_bfloat16*)out)[n*CC + c] = __float2bfloat16(qv[c]);
        }
    } else {
        float s = 0.f;
        #pragma unroll
        for (int c = 0; c < CC; c++) { qv[c] = fexp(qv[c] - mx); s += qv[c]; }
        float inv = 1.f / s;
        #pragma unroll
        for (int c = 0; c < CC; c++)
            pT[(size_t)c*NN + n] = __float2bfloat16(qv[c] * inv);
    }
}

extern "C" void kernel_launch(void* const* d_in, const int* in_sizes, int n_in,
                              void* d_out, int out_size, void* d_ws, size_t ws_size,
                              hipStream_t stream)
{
    float* ws = (float*)d_ws;
    int*   flag  = (int*)ws;                     // [0..16)
    float* par   = ws + 16;                      // [16..528)
    float* featx = ws + 528;                     // NN*8
    __hip_bfloat16* pT = (__hip_bfloat16*)(ws + 528 + NN*8);  // 32*NN bf16
    float* uf  = ws + 528 + NN*8 + 16*NN;        // NELEM
    float* s2T = uf + NELEM;                     // NELEM (c-major)
    float* bil = s2T + NELEM;                    // NELEM (c-major)
    // total ~ 0.84 MB floats -> ~3.2 MB

    k_sniff<<<1, 1024, 0, stream>>>((const unsigned short*)d_in[0], flag);
    k_prep<<<NN/256, 256, 0, stream>>>(d_in[0], d_in[1], d_in[2], d_in[3], d_in[4],
                                       flag, uf, featx, par, bil, pT);

    for (int it = 0; it < 5; it++) {
        k_work<<<NBB + NBLUR, 256, 0, stream>>>(pT, featx, bil, s2T);
        k_update<<<NN/256, 256, 0, stream>>>(bil, s2T, uf, par, flag,
                                             pT, d_out, (it == 4) ? 1 : 0);
    }
}